// Round 8
// baseline (175.583 us; speedup 1.0000x reference)
//
#include <hip/hip_runtime.h>

// MPS tensor-train classifier, B=16384, D=784, BOND=5, OUT=10.
//
// Round-11: DUAL-ROW + SMEM coefficients = halve per-CU coefficient
// traffic. Five structures (r1 LDS, r7 SMEM, r9 SMEM+split, r10 hybrid)
// all pinned at ~47-50 us because per-CU coefficient delivery (25 quads x
// 390 pairs x every resident 64-row group) is invariant: ~9.75-19.5k
// loads/CU -> ~100-117k cycles of pipe service time. Only amortizing one
// fetch across MORE ROWS reduces it. Round-5/6 tried this via LDS
// broadcast and died of VGPR blowup (dual CMat + staging ~200 floats).
// Here: coefficients stay in SGPRs (s_load, uniform addr); rows processed
// SEQUENTIALLY per pair: build C_A (30 VGPR) -> in-place matmul on MA
// (5 temps) -> rebuild C_B from the SAME SGPRs -> MB. Peak live ~95
// floats, fits (1024,4)'s 128-VGPR budget. s_load traffic per pair is
// ONE 25-quad set serving two rows -> per-CU traffic halves.
//
//   256 blocks x 1024 thr; block = {row-group g (128 rows: rowA, rowA+64),
//   half h}. wave 0 = vec chain (15 pairs + boundary, dual-row);
//   waves 1..15 = 12-pair matrix chains (dual-row). Combine: 3 phases x
//   5 slots, matbuf[5][25][128] = 62.5 KB. vL -> out-flat[0:81920),
//   wR -> out-flat[81920:163840); finish_dot + finish_out as r9.
//
// pk layout (100 floats/pair), q = 0..3 (coeff of 1, xa, xb, xa*xb):
//   rows:  q*20 + l*4 + r  (quad s4[q*5+l]); col4: 80 + l*4 + q (s4[20+l],
//   l-major); (4,4): 96 + q (s4[24]).

typedef float v4f __attribute__((ext_vector_type(4)));
typedef float v2f __attribute__((ext_vector_type(2)));

constexpr int Bn     = 16384;
constexpr int Dn     = 784;
constexpr int NOUT   = 10;
constexpr int NPAIR  = 390;   // pairs cover sites 1..780
constexpr int PVEC   = 15;    // vec-wave pairs per half
constexpr int PMAT   = 12;    // pairs per matrix wave (15 waves per half)
constexpr int RHP0   = 195;   // right half first pair
constexpr int BWD_P0 = 375;   // pairs >= this stored transposed (right vec)
constexpr int PAIR_F = 100;   // floats per pair block
constexpr int WROFF  = Bn * 5; // wR stash offset (floats) in out

__device__ __forceinline__ v4f splat4(float x) { v4f v = {x, x, x, x}; return v; }
__device__ __forceinline__ v4f fma4(v4f a, v4f b, v4f c) {
    return __builtin_elementwise_fma(a, b, c);
}

struct Frag { v4f r[5]; float c4[5]; };          // 5x5 running product
struct CMat { v4f row[5]; v4f c4v; float c44; }; // 5x5 pair matrix

// Build full C from uniform (SGPR) coefficients + per-lane xa,xb.
__device__ __forceinline__ void build_C(CMat& C, const float* __restrict__ s,
                                        v2f xc) {
    const float xa = xc[0], xb = xc[1], xab = xa * xb;
    const v4f va = splat4(xa), vb = splat4(xb), vp = splat4(xab);
    const v4f* s4 = (const v4f*)s;
#pragma unroll
    for (int l = 0; l < 5; ++l)
        C.row[l] = fma4(vp, s4[15 + l], fma4(vb, s4[10 + l], fma4(va, s4[5 + l], s4[l])));
#pragma unroll
    for (int l = 0; l < 4; ++l) {
        v4f cq = s4[20 + l];
        C.c4v[l] = fmaf(xab, cq[3], fmaf(xb, cq[2], fmaf(xa, cq[1], cq[0])));
    }
    {
        v4f cq = s4[24];
        C.c44 = fmaf(xab, cq[3], fmaf(xb, cq[2], fmaf(xa, cq[1], cq[0])));
    }
}

// M = M @ C, in place (output row i depends only on input row i; 5 temps)
__device__ __forceinline__ void matmulIP(Frag& M, const CMat& C) {
#pragma unroll
    for (int i = 0; i < 5; ++i) {
        v4f acc  = splat4(M.r[i][0]) * C.row[0];
        float a4 = M.r[i][0] * C.c4v[0];
#pragma unroll
        for (int l = 1; l < 4; ++l) {
            acc = fma4(splat4(M.r[i][l]), C.row[l], acc);
            a4  = fmaf(M.r[i][l], C.c4v[l], a4);
        }
        acc = fma4(splat4(M.c4[i]), C.row[4], acc);
        a4  = fmaf(M.c4[i], C.c44, a4);
        M.r[i] = acc; M.c4[i] = a4;
    }
}

// c' = c @ C   (row vector)
__device__ __forceinline__ void vecstepC(v4f& cv, float& c4, const CMat& C) {
    v4f acc  = splat4(cv[0]) * C.row[0];
    float a4 = cv[0] * C.c4v[0];
#pragma unroll
    for (int l = 1; l < 4; ++l) {
        acc = fma4(splat4(cv[l]), C.row[l], acc);
        a4  = fmaf(cv[l], C.c4v[l], a4);
    }
    acc = fma4(splat4(c4), C.row[4], acc);
    a4  = fmaf(c4, C.c44, a4);
    cv = acc; c4 = a4;
}

// ---- prepack: build pair blocks (transposed for p >= BWD_P0) ----
// cores_mid element (m,l,i,k) at (m*5+l)*10 + i*5 + k
__global__ void prepack_pairs(const float* __restrict__ cm, float* __restrict__ pk)
{
    int idx = blockIdx.x * 256 + threadIdx.x;
    if (idx >= NPAIR * 100) return;
    int p = idx / 100, rest = idx - p * 100;
    int q = rest / 25, e = rest - q * 25;
    int l = e / 5, r = e - l * 5;
    int m1 = 2 * p + 1, m2 = 2 * p + 2;
    const float* L = cm + (size_t)(m1 * 5 + l) * 10;
    float acc = 0.f;
#pragma unroll
    for (int k = 0; k < 5; ++k) {
        float Lk = (q & 1) ? (L[5 + k] - L[k]) : L[k];
        const float* R = cm + (size_t)(m2 * 5 + k) * 10;
        float Rk = (q & 2) ? (R[5 + r] - R[r]) : R[r];
        acc = fmaf(Lk, Rk, acc);
    }
    int wl = l, wr = r;
    if (p >= BWD_P0) { wl = r; wr = l; }   // store C^T for right vec wave
    int off;
    if (wr < 4)      off = q * 20 + wl * 4 + wr;
    else if (wl < 4) off = 80 + wl * 4 + q;   // col4, l-major
    else             off = 96 + q;            // c44 quad
    pk[(size_t)p * PAIR_F + off] = acc;
}

__global__ __launch_bounds__(1024, 4)
void mps_half_kernel(const float* __restrict__ x,          // [B, D]
                     const float* __restrict__ core_first, // [2,5]
                     const float* __restrict__ cores_mid,  // [782,5,2,5]
                     const float* __restrict__ core_last,  // [5,2]
                     const float* __restrict__ pk,         // [390][100]
                     float* __restrict__ out)              // [B,10] used as stash
{
    __shared__ float matbuf[5][25][128];  // 62.5 KB combine matrices

    const int lane = threadIdx.x & 63;
    const int wave = threadIdx.x >> 6;
    const int wu   = __builtin_amdgcn_readfirstlane(wave);  // uniform wave id
    const int g    = blockIdx.x >> 1;
    const int h    = blockIdx.x & 1;
    const int rowA = g * 128 + lane;
    const int rowB = rowA + 64;
    const v2f* __restrict__ xA2 = (const v2f*)(x + (size_t)rowA * Dn);
    const v2f* __restrict__ xB2 = (const v2f*)(x + (size_t)rowB * Dn);

    if (wu >= 1) {
        // ---- matrix wave: 12 pairs, dual-row, shared SMEM coefficients ----
        const int p0 = (h == 0 ? PVEC : RHP0) + PMAT * (wu - 1);  // uniform

        Frag MA, MB;
        MA.r[0] = {1,0,0,0}; MA.r[1] = {0,1,0,0}; MA.r[2] = {0,0,1,0};
        MA.r[3] = {0,0,0,1}; MA.r[4] = {0,0,0,0};
        MA.c4[0] = 0; MA.c4[1] = 0; MA.c4[2] = 0; MA.c4[3] = 0; MA.c4[4] = 1;
        MB = MA;

        v2f xA = xA2[p0 + 1], xB = xB2[p0 + 1];
#pragma unroll 1
        for (int j = 0; j < PMAT; ++j) {
            const float* s = pk + (size_t)(p0 + j) * PAIR_F;   // uniform addr
            v2f nxA = xA2[p0 + j + 2], nxB = xB2[p0 + j + 2];  // x prefetch
            CMat C;
            build_C(C, s, xA);  matmulIP(MA, C);
            build_C(C, s, xB);  matmulIP(MB, C);   // same SGPR quads
            xA = nxA; xB = nxB;
        }

        // slot phase/index: left vec consumes slots ascending (waves 1..15),
        // right vec descending (15..1); 3 phases of 5 slots.
        const int ord = (h == 0) ? (wu - 1) : (15 - wu);
        const int ph  = ord / 5;
        const int k   = ord - ph * 5;
        if (ph == 0) {
#pragma unroll
            for (int i = 0; i < 5; ++i) {
#pragma unroll
                for (int r = 0; r < 4; ++r) {
                    matbuf[k][i * 5 + r][lane]      = MA.r[i][r];
                    matbuf[k][i * 5 + r][lane + 64] = MB.r[i][r];
                }
                matbuf[k][i * 5 + 4][lane]      = MA.c4[i];
                matbuf[k][i * 5 + 4][lane + 64] = MB.c4[i];
            }
        }
        __syncthreads();   // b1: phase-0 slots ready
        __syncthreads();   // b2: vec finished reading phase-0
        if (ph == 1) {
#pragma unroll
            for (int i = 0; i < 5; ++i) {
#pragma unroll
                for (int r = 0; r < 4; ++r) {
                    matbuf[k][i * 5 + r][lane]      = MA.r[i][r];
                    matbuf[k][i * 5 + r][lane + 64] = MB.r[i][r];
                }
                matbuf[k][i * 5 + 4][lane]      = MA.c4[i];
                matbuf[k][i * 5 + 4][lane + 64] = MB.c4[i];
            }
        }
        __syncthreads();   // b3: phase-1 slots ready
        __syncthreads();   // b4: vec finished reading phase-1
        if (ph == 2) {
#pragma unroll
            for (int i = 0; i < 5; ++i) {
#pragma unroll
                for (int r = 0; r < 4; ++r) {
                    matbuf[k][i * 5 + r][lane]      = MA.r[i][r];
                    matbuf[k][i * 5 + r][lane + 64] = MB.r[i][r];
                }
                matbuf[k][i * 5 + 4][lane]      = MA.c4[i];
                matbuf[k][i * 5 + 4][lane + 64] = MB.c4[i];
            }
        }
        __syncthreads();   // b5: phase-2 slots ready
    } else if (h == 0) {
        // ---- left vec wave: carry0, site 0, pairs 0..14, combine asc ----
        v2f xA01 = xA2[0], xB01 = xB2[0];
        float clA[5], clB[5], cnA[5], cnB[5];
#pragma unroll
        for (int r = 0; r < 5; ++r) {
            float d = core_first[5 + r] - core_first[r];
            clA[r] = fmaf(xA01[0], d, core_first[r]);
            clB[r] = fmaf(xB01[0], d, core_first[r]);
        }
        const float* cm0 = cores_mid;                      // site 0
#pragma unroll
        for (int r = 0; r < 5; ++r) {
            float aA = 0.f, aB = 0.f;
#pragma unroll
            for (int l = 0; l < 5; ++l) {
                float base = cm0[l * 10 + r], d = cm0[l * 10 + 5 + r] - base;
                aA = fmaf(clA[l], fmaf(xA01[1], d, base), aA);
                aB = fmaf(clB[l], fmaf(xB01[1], d, base), aB);
            }
            cnA[r] = aA; cnB[r] = aB;
        }
        v4f cvA = {cnA[0], cnA[1], cnA[2], cnA[3]};
        v4f cvB = {cnB[0], cnB[1], cnB[2], cnB[3]};
        float c4A = cnA[4], c4B = cnB[4];

        v2f xA = xA2[1], xB = xB2[1];
#pragma unroll 1
        for (int p = 0; p < PVEC; ++p) {
            const float* s = pk + (size_t)p * PAIR_F;
            v2f nxA = xA2[p + 2], nxB = xB2[p + 2];
            CMat C;
            build_C(C, s, xA);  vecstepC(cvA, c4A, C);
            build_C(C, s, xB);  vecstepC(cvB, c4B, C);
            xA = nxA; xB = nxB;
        }
        clA[0] = cvA[0]; clA[1] = cvA[1]; clA[2] = cvA[2]; clA[3] = cvA[3]; clA[4] = c4A;
        clB[0] = cvB[0]; clB[1] = cvB[1]; clB[2] = cvB[2]; clB[3] = cvB[3]; clB[4] = c4B;

#pragma unroll 1
        for (int phase = 0; phase < 3; ++phase) {
            __syncthreads();                 // b1 / b3 / b5 entry
#pragma unroll 1
            for (int k = 0; k < 5; ++k) {
                float vA[5], vB[5];
#pragma unroll
                for (int r = 0; r < 5; ++r) {
                    vA[r] = clA[0] * matbuf[k][r][lane];
                    vB[r] = clB[0] * matbuf[k][r][lane + 64];
                }
#pragma unroll
                for (int l = 1; l < 5; ++l)
#pragma unroll
                    for (int r = 0; r < 5; ++r) {
                        vA[r] = fmaf(clA[l], matbuf[k][l * 5 + r][lane],      vA[r]);
                        vB[r] = fmaf(clB[l], matbuf[k][l * 5 + r][lane + 64], vB[r]);
                    }
#pragma unroll
                for (int r = 0; r < 5; ++r) { clA[r] = vA[r]; clB[r] = vB[r]; }
            }
            if (phase < 2) __syncthreads();  // b2 / b4: release writers
        }
        float* oA = out + (size_t)rowA * 5;                // vL stash (flat)
        float* oB = out + (size_t)rowB * 5;
#pragma unroll
        for (int i = 0; i < 5; ++i) { oA[i] = clA[i]; oB[i] = clB[i]; }
    } else {
        // ---- right vec wave: vlast, site 781, pairs 389..375 desc,
        //      combine desc (3 phases, column form) ----
        v2f xAz = xA2[391], xBz = xB2[391];                // {x782, x783}
        float vlA[5], vlB[5], vnA[5], vnB[5];
#pragma unroll
        for (int l = 0; l < 5; ++l) {
            float base = core_last[2 * l], d = core_last[2 * l + 1] - base;
            vlA[l] = fmaf(xAz[1], d, base);
            vlB[l] = fmaf(xBz[1], d, base);
        }
        const float* cmL = cores_mid + (size_t)781 * 50;
#pragma unroll
        for (int l = 0; l < 5; ++l) {
            float aA = 0.f, aB = 0.f;
#pragma unroll
            for (int r = 0; r < 5; ++r) {
                float base = cmL[l * 10 + r], d = cmL[l * 10 + 5 + r] - base;
                aA = fmaf(fmaf(xAz[0], d, base), vlA[r], aA);
                aB = fmaf(fmaf(xBz[0], d, base), vlB[r], aB);
            }
            vnA[l] = aA; vnB[l] = aB;
        }
        v4f cvA = {vnA[0], vnA[1], vnA[2], vnA[3]};
        v4f cvB = {vnB[0], vnB[1], vnB[2], vnB[3]};
        float c4A = vnA[4], c4B = vnB[4];

        v2f xA = xA2[390], xB = xB2[390];
#pragma unroll 1
        for (int p = 389; p >= BWD_P0; --p) {              // transposed storage
            const float* s = pk + (size_t)p * PAIR_F;
            v2f nxA = xA2[p], nxB = xB2[p];                // x for pair p-1
            CMat C;
            build_C(C, s, xA);  vecstepC(cvA, c4A, C);
            build_C(C, s, xB);  vecstepC(cvB, c4B, C);
            xA = nxA; xB = nxB;
        }
        float uA[5] = {cvA[0], cvA[1], cvA[2], cvA[3], c4A};
        float uB[5] = {cvB[0], cvB[1], cvB[2], cvB[3], c4B};

#pragma unroll 1
        for (int phase = 0; phase < 3; ++phase) {
            __syncthreads();                 // b1 / b3 / b5 entry
#pragma unroll 1
            for (int k = 0; k < 5; ++k) {                  // u = M_slot @ u
                float vA[5], vB[5];
#pragma unroll
                for (int i = 0; i < 5; ++i) {
                    float aA = matbuf[k][i * 5][lane]      * uA[0];
                    float aB = matbuf[k][i * 5][lane + 64] * uB[0];
#pragma unroll
                    for (int l = 1; l < 5; ++l) {
                        aA = fmaf(matbuf[k][i * 5 + l][lane],      uA[l], aA);
                        aB = fmaf(matbuf[k][i * 5 + l][lane + 64], uB[l], aB);
                    }
                    vA[i] = aA; vB[i] = aB;
                }
#pragma unroll
                for (int i = 0; i < 5; ++i) { uA[i] = vA[i]; uB[i] = vB[i]; }
            }
            if (phase < 2) __syncthreads();  // b2 / b4: release writers
        }
        float* oA = out + WROFF + (size_t)rowA * 5;        // wR stash (flat)
        float* oB = out + WROFF + (size_t)rowB * 5;
#pragma unroll
        for (int i = 0; i < 5; ++i) { oA[i] = uA[i]; oB[i] = uB[i]; }
    }
}

// ---- stage 2a: res[r] = vL . wR (res overwrites dead pk region of ws) ----
__global__ __launch_bounds__(256)
void finish_dot(const float* __restrict__ outF, float* __restrict__ res)
{
    int r = blockIdx.x * 256 + threadIdx.x;
    const float* vl = outF + (size_t)r * 5;
    const float* wr = outF + WROFF + (size_t)r * 5;
    float s = vl[0] * wr[0];
#pragma unroll
    for (int i = 1; i < 5; ++i) s = fmaf(vl[i], wr[i], s);
    res[r] = s;
}

// ---- stage 2b: out = res*fc_w + fc_b ----
__global__ __launch_bounds__(256)
void finish_out(const float* __restrict__ res, const float* __restrict__ fc_w,
                const float* __restrict__ fc_b, float* __restrict__ out)
{
    int r = blockIdx.x * 256 + threadIdx.x;
    float rv = res[r];
    float* o = out + (size_t)r * NOUT;
#pragma unroll
    for (int j = 0; j < NOUT; ++j) o[j] = fmaf(rv, fc_w[j], fc_b[j]);
}

extern "C" void kernel_launch(void* const* d_in, const int* in_sizes, int n_in,
                              void* d_out, int out_size, void* d_ws, size_t ws_size,
                              hipStream_t stream) {
    const float* x          = (const float*)d_in[0];
    const float* core_first = (const float*)d_in[1];
    const float* cores_mid  = (const float*)d_in[2];
    const float* core_last  = (const float*)d_in[3];
    const float* fc_w       = (const float*)d_in[4];
    const float* fc_b       = (const float*)d_in[5];
    float* out              = (float*)d_out;
    float* pk               = (float*)d_ws;   // 390*100*4 = 156,000 B
    float* res              = (float*)d_ws;   // reuses pk region (dead after main)

    hipLaunchKernelGGL(prepack_pairs, dim3((NPAIR * 100 + 255) / 256), dim3(256),
                       0, stream, cores_mid, pk);
    hipLaunchKernelGGL(mps_half_kernel, dim3(256), dim3(1024), 0, stream,
                       x, core_first, cores_mid, core_last, pk, out);
    hipLaunchKernelGGL(finish_dot, dim3(Bn / 256), dim3(256), 0, stream,
                       out, res);
    hipLaunchKernelGGL(finish_out, dim3(Bn / 256), dim3(256), 0, stream,
                       res, fc_w, fc_b, out);
}

// Round 9
// 146.000 us; speedup vs baseline: 1.2026x; 1.2026x over previous
//
#include <hip/hip_runtime.h>

// MPS tensor-train classifier, B=16384, D=784, BOND=5, OUT=10.
//
// Round-12: dual-row + SGPR coefficients, 512-THREAD blocks.
// The ~47us plateau (r1 LDS, r7 SMEM, r9 split, r10 hybrid) is explained
// by per-CU coefficient delivery: ~9750 quad-fetches/CU x ~12cyc ~ 117k
// cyc ~ 47us, invariant across pipe choice. Halving it needs one fetch to
// serve 2 rows (dual-row). r5/r6/r11 all died of VGPR spills because the
// allocator caps 1024-thr blocks at 64 VGPR (observed 5x) while dual-row
// needs ~100 live floats. Round-2 precedent: 512-thr blocks get 128 VGPR.
//   256 blocks x 512 thr (8 waves); block = {row-group g (rows g*128+lane,
//   +64), half h}. Wave 0: vec chain, dual-row, 20 pairs + boundary.
//   Waves 1..7: 25-pair matrix chains, dual-row: build C_A from SGPR
//   quads -> MA; rebuild C_B from SAME quads -> MB (coeff fetch amortized
//   over 2 rows -> per-CU s_load traffic halves to 4875).
//   Combine: matbuf[4][25][128] = 51.2 KB, 2 phases (4+3 slots), 3 bars.
//   vL -> out-flat[0:81920); wR -> out-flat[81920:163840).
//   finish_dot (res -> dead pk region of ws) + finish_out.
//
// pk layout (100 floats/pair), q = 0..3 (coeff of 1, xa, xb, xa*xb):
//   rows:  q*20 + l*4 + r  (quad s4[q*5+l]); col4: 80 + l*4 + q (s4[20+l],
//   l-major); (4,4): 96 + q (s4[24]).

typedef float v4f __attribute__((ext_vector_type(4)));
typedef float v2f __attribute__((ext_vector_type(2)));

constexpr int Bn     = 16384;
constexpr int Dn     = 784;
constexpr int NOUT   = 10;
constexpr int NPAIR  = 390;   // pairs cover sites 1..780
constexpr int PVEC   = 20;    // vec-wave pairs per half
constexpr int PMAT   = 25;    // pairs per matrix wave (7 waves per half)
constexpr int RHP0   = 195;   // right half first pair
constexpr int BWD_P0 = 370;   // pairs >= this stored transposed (right vec)
constexpr int PAIR_F = 100;   // floats per pair block
constexpr int WROFF  = Bn * 5; // wR stash offset (floats) in out

__device__ __forceinline__ v4f splat4(float x) { v4f v = {x, x, x, x}; return v; }
__device__ __forceinline__ v4f fma4(v4f a, v4f b, v4f c) {
    return __builtin_elementwise_fma(a, b, c);
}

struct Frag { v4f r[5]; float c4[5]; };          // 5x5 running product
struct CMat { v4f row[5]; v4f c4v; float c44; }; // 5x5 pair matrix

// Build full C from uniform (SGPR) coefficients + per-lane xa,xb.
__device__ __forceinline__ void build_C(CMat& C, const float* __restrict__ s,
                                        v2f xc) {
    const float xa = xc[0], xb = xc[1], xab = xa * xb;
    const v4f va = splat4(xa), vb = splat4(xb), vp = splat4(xab);
    const v4f* s4 = (const v4f*)s;
#pragma unroll
    for (int l = 0; l < 5; ++l)
        C.row[l] = fma4(vp, s4[15 + l], fma4(vb, s4[10 + l], fma4(va, s4[5 + l], s4[l])));
#pragma unroll
    for (int l = 0; l < 4; ++l) {
        v4f cq = s4[20 + l];
        C.c4v[l] = fmaf(xab, cq[3], fmaf(xb, cq[2], fmaf(xa, cq[1], cq[0])));
    }
    {
        v4f cq = s4[24];
        C.c44 = fmaf(xab, cq[3], fmaf(xb, cq[2], fmaf(xa, cq[1], cq[0])));
    }
}

// M = M @ C, in place (output row i depends only on input row i; 5 temps)
__device__ __forceinline__ void matmulIP(Frag& M, const CMat& C) {
#pragma unroll
    for (int i = 0; i < 5; ++i) {
        v4f acc  = splat4(M.r[i][0]) * C.row[0];
        float a4 = M.r[i][0] * C.c4v[0];
#pragma unroll
        for (int l = 1; l < 4; ++l) {
            acc = fma4(splat4(M.r[i][l]), C.row[l], acc);
            a4  = fmaf(M.r[i][l], C.c4v[l], a4);
        }
        acc = fma4(splat4(M.c4[i]), C.row[4], acc);
        a4  = fmaf(M.c4[i], C.c44, a4);
        M.r[i] = acc; M.c4[i] = a4;
    }
}

// c' = c @ C   (row vector)
__device__ __forceinline__ void vecstepC(v4f& cv, float& c4, const CMat& C) {
    v4f acc  = splat4(cv[0]) * C.row[0];
    float a4 = cv[0] * C.c4v[0];
#pragma unroll
    for (int l = 1; l < 4; ++l) {
        acc = fma4(splat4(cv[l]), C.row[l], acc);
        a4  = fmaf(cv[l], C.c4v[l], a4);
    }
    acc = fma4(splat4(c4), C.row[4], acc);
    a4  = fmaf(c4, C.c44, a4);
    cv = acc; c4 = a4;
}

// ---- prepack: build pair blocks (transposed for p >= BWD_P0) ----
// cores_mid element (m,l,i,k) at (m*5+l)*10 + i*5 + k
__global__ void prepack_pairs(const float* __restrict__ cm, float* __restrict__ pk)
{
    int idx = blockIdx.x * 256 + threadIdx.x;
    if (idx >= NPAIR * 100) return;
    int p = idx / 100, rest = idx - p * 100;
    int q = rest / 25, e = rest - q * 25;
    int l = e / 5, r = e - l * 5;
    int m1 = 2 * p + 1, m2 = 2 * p + 2;
    const float* L = cm + (size_t)(m1 * 5 + l) * 10;
    float acc = 0.f;
#pragma unroll
    for (int k = 0; k < 5; ++k) {
        float Lk = (q & 1) ? (L[5 + k] - L[k]) : L[k];
        const float* R = cm + (size_t)(m2 * 5 + k) * 10;
        float Rk = (q & 2) ? (R[5 + r] - R[r]) : R[r];
        acc = fmaf(Lk, Rk, acc);
    }
    int wl = l, wr = r;
    if (p >= BWD_P0) { wl = r; wr = l; }   // store C^T for right vec wave
    int off;
    if (wr < 4)      off = q * 20 + wl * 4 + wr;
    else if (wl < 4) off = 80 + wl * 4 + q;   // col4, l-major
    else             off = 96 + q;            // c44 quad
    pk[(size_t)p * PAIR_F + off] = acc;
}

__global__ __launch_bounds__(512, 2)
void mps_half_kernel(const float* __restrict__ x,          // [B, D]
                     const float* __restrict__ core_first, // [2,5]
                     const float* __restrict__ cores_mid,  // [782,5,2,5]
                     const float* __restrict__ core_last,  // [5,2]
                     const float* __restrict__ pk,         // [390][100]
                     float* __restrict__ out)              // [B,10] used as stash
{
    __shared__ float matbuf[4][25][128];  // 51.2 KB combine matrices

    const int lane = threadIdx.x & 63;
    const int wave = threadIdx.x >> 6;    // 0..7
    const int wu   = __builtin_amdgcn_readfirstlane(wave);  // uniform wave id
    const int g    = blockIdx.x >> 1;
    const int h    = blockIdx.x & 1;
    const int rowA = g * 128 + lane;
    const int rowB = rowA + 64;
    const v2f* __restrict__ xA2 = (const v2f*)(x + (size_t)rowA * Dn);
    const v2f* __restrict__ xB2 = (const v2f*)(x + (size_t)rowB * Dn);

    if (wu >= 1) {
        // ---- matrix wave: 25 pairs, dual-row, shared SGPR coefficients ----
        const int p0 = (h == 0 ? PVEC : RHP0) + PMAT * (wu - 1);  // uniform

        Frag MA, MB;
        MA.r[0] = {1,0,0,0}; MA.r[1] = {0,1,0,0}; MA.r[2] = {0,0,1,0};
        MA.r[3] = {0,0,0,1}; MA.r[4] = {0,0,0,0};
        MA.c4[0] = 0; MA.c4[1] = 0; MA.c4[2] = 0; MA.c4[3] = 0; MA.c4[4] = 1;
        MB = MA;

        v2f xA = xA2[p0 + 1], xB = xB2[p0 + 1];
#pragma unroll 1
        for (int j = 0; j < PMAT; ++j) {
            const float* s = pk + (size_t)(p0 + j) * PAIR_F;   // uniform addr
            v2f nxA = xA2[p0 + j + 2], nxB = xB2[p0 + j + 2];  // x prefetch
            CMat C;
            build_C(C, s, xA);  matmulIP(MA, C);
            build_C(C, s, xB);  matmulIP(MB, C);   // same SGPR quads
            xA = nxA; xB = nxB;
        }

        // consumption order: left vec folds slots 1..7 asc; right 7..1 desc.
        const int ord  = (h == 0) ? (wu - 1) : (7 - wu);
        const bool ph1 = (ord < 4);
        const int  k   = ph1 ? ord : ord - 4;
        if (ph1) {
#pragma unroll
            for (int i = 0; i < 5; ++i) {
#pragma unroll
                for (int r = 0; r < 4; ++r) {
                    matbuf[k][i * 5 + r][lane]      = MA.r[i][r];
                    matbuf[k][i * 5 + r][lane + 64] = MB.r[i][r];
                }
                matbuf[k][i * 5 + 4][lane]      = MA.c4[i];
                matbuf[k][i * 5 + 4][lane + 64] = MB.c4[i];
            }
        }
        __syncthreads();   // b1: phase-1 slots ready
        __syncthreads();   // b2: vec finished reading phase-1
        if (!ph1) {
#pragma unroll
            for (int i = 0; i < 5; ++i) {
#pragma unroll
                for (int r = 0; r < 4; ++r) {
                    matbuf[k][i * 5 + r][lane]      = MA.r[i][r];
                    matbuf[k][i * 5 + r][lane + 64] = MB.r[i][r];
                }
                matbuf[k][i * 5 + 4][lane]      = MA.c4[i];
                matbuf[k][i * 5 + 4][lane + 64] = MB.c4[i];
            }
        }
        __syncthreads();   // b3: phase-2 slots ready
    } else if (h == 0) {
        // ---- left vec wave: carry0, site 0, pairs 0..19, combine asc ----
        v2f xA01 = xA2[0], xB01 = xB2[0];
        float clA[5], clB[5], cnA[5], cnB[5];
#pragma unroll
        for (int r = 0; r < 5; ++r) {
            float d = core_first[5 + r] - core_first[r];
            clA[r] = fmaf(xA01[0], d, core_first[r]);
            clB[r] = fmaf(xB01[0], d, core_first[r]);
        }
        const float* cm0 = cores_mid;                      // site 0
#pragma unroll
        for (int r = 0; r < 5; ++r) {
            float aA = 0.f, aB = 0.f;
#pragma unroll
            for (int l = 0; l < 5; ++l) {
                float base = cm0[l * 10 + r], d = cm0[l * 10 + 5 + r] - base;
                aA = fmaf(clA[l], fmaf(xA01[1], d, base), aA);
                aB = fmaf(clB[l], fmaf(xB01[1], d, base), aB);
            }
            cnA[r] = aA; cnB[r] = aB;
        }
        v4f cvA = {cnA[0], cnA[1], cnA[2], cnA[3]};
        v4f cvB = {cnB[0], cnB[1], cnB[2], cnB[3]};
        float c4A = cnA[4], c4B = cnB[4];

        v2f xA = xA2[1], xB = xB2[1];
#pragma unroll 1
        for (int p = 0; p < PVEC; ++p) {
            const float* s = pk + (size_t)p * PAIR_F;
            v2f nxA = xA2[p + 2], nxB = xB2[p + 2];
            CMat C;
            build_C(C, s, xA);  vecstepC(cvA, c4A, C);
            build_C(C, s, xB);  vecstepC(cvB, c4B, C);
            xA = nxA; xB = nxB;
        }
        clA[0] = cvA[0]; clA[1] = cvA[1]; clA[2] = cvA[2]; clA[3] = cvA[3]; clA[4] = c4A;
        clB[0] = cvB[0]; clB[1] = cvB[1]; clB[2] = cvB[2]; clB[3] = cvB[3]; clB[4] = c4B;

        __syncthreads();   // b1: phase-1 slots (waves 1..4 at k=0..3)
#pragma unroll 1
        for (int k = 0; k < 4; ++k) {
            float vA[5], vB[5];
#pragma unroll
            for (int r = 0; r < 5; ++r) {
                vA[r] = clA[0] * matbuf[k][r][lane];
                vB[r] = clB[0] * matbuf[k][r][lane + 64];
            }
#pragma unroll
            for (int l = 1; l < 5; ++l)
#pragma unroll
                for (int r = 0; r < 5; ++r) {
                    vA[r] = fmaf(clA[l], matbuf[k][l * 5 + r][lane],      vA[r]);
                    vB[r] = fmaf(clB[l], matbuf[k][l * 5 + r][lane + 64], vB[r]);
                }
#pragma unroll
            for (int r = 0; r < 5; ++r) { clA[r] = vA[r]; clB[r] = vB[r]; }
        }
        __syncthreads();   // b2: release phase-2 writers
        __syncthreads();   // b3: phase-2 slots (waves 5..7 at k=0..2)
#pragma unroll 1
        for (int k = 0; k < 3; ++k) {
            float vA[5], vB[5];
#pragma unroll
            for (int r = 0; r < 5; ++r) {
                vA[r] = clA[0] * matbuf[k][r][lane];
                vB[r] = clB[0] * matbuf[k][r][lane + 64];
            }
#pragma unroll
            for (int l = 1; l < 5; ++l)
#pragma unroll
                for (int r = 0; r < 5; ++r) {
                    vA[r] = fmaf(clA[l], matbuf[k][l * 5 + r][lane],      vA[r]);
                    vB[r] = fmaf(clB[l], matbuf[k][l * 5 + r][lane + 64], vB[r]);
                }
#pragma unroll
            for (int r = 0; r < 5; ++r) { clA[r] = vA[r]; clB[r] = vB[r]; }
        }
        float* oA = out + (size_t)rowA * 5;                // vL stash (flat)
        float* oB = out + (size_t)rowB * 5;
#pragma unroll
        for (int i = 0; i < 5; ++i) { oA[i] = clA[i]; oB[i] = clB[i]; }
    } else {
        // ---- right vec wave: vlast, site 781, pairs 389..370 desc,
        //      combine desc (2 phases, column form) ----
        v2f xAz = xA2[391], xBz = xB2[391];                // {x782, x783}
        float vlA[5], vlB[5], vnA[5], vnB[5];
#pragma unroll
        for (int l = 0; l < 5; ++l) {
            float base = core_last[2 * l], d = core_last[2 * l + 1] - base;
            vlA[l] = fmaf(xAz[1], d, base);
            vlB[l] = fmaf(xBz[1], d, base);
        }
        const float* cmL = cores_mid + (size_t)781 * 50;
#pragma unroll
        for (int l = 0; l < 5; ++l) {
            float aA = 0.f, aB = 0.f;
#pragma unroll
            for (int r = 0; r < 5; ++r) {
                float base = cmL[l * 10 + r], d = cmL[l * 10 + 5 + r] - base;
                aA = fmaf(fmaf(xAz[0], d, base), vlA[r], aA);
                aB = fmaf(fmaf(xBz[0], d, base), vlB[r], aB);
            }
            vnA[l] = aA; vnB[l] = aB;
        }
        v4f cvA = {vnA[0], vnA[1], vnA[2], vnA[3]};
        v4f cvB = {vnB[0], vnB[1], vnB[2], vnB[3]};
        float c4A = vnA[4], c4B = vnB[4];

        v2f xA = xA2[390], xB = xB2[390];
#pragma unroll 1
        for (int p = 389; p >= BWD_P0; --p) {              // transposed storage
            const float* s = pk + (size_t)p * PAIR_F;
            v2f nxA = xA2[p], nxB = xB2[p];                // x for pair p-1
            CMat C;
            build_C(C, s, xA);  vecstepC(cvA, c4A, C);
            build_C(C, s, xB);  vecstepC(cvB, c4B, C);
            xA = nxA; xB = nxB;
        }
        float uA[5] = {cvA[0], cvA[1], cvA[2], cvA[3], c4A};
        float uB[5] = {cvB[0], cvB[1], cvB[2], cvB[3], c4B};

        __syncthreads();   // b1: phase-1 slots (waves 7..4 at k=0..3)
#pragma unroll 1
        for (int k = 0; k < 4; ++k) {                      // u = M_slot @ u
            float vA[5], vB[5];
#pragma unroll
            for (int i = 0; i < 5; ++i) {
                float aA = matbuf[k][i * 5][lane]      * uA[0];
                float aB = matbuf[k][i * 5][lane + 64] * uB[0];
#pragma unroll
                for (int l = 1; l < 5; ++l) {
                    aA = fmaf(matbuf[k][i * 5 + l][lane],      uA[l], aA);
                    aB = fmaf(matbuf[k][i * 5 + l][lane + 64], uB[l], aB);
                }
                vA[i] = aA; vB[i] = aB;
            }
#pragma unroll
            for (int i = 0; i < 5; ++i) { uA[i] = vA[i]; uB[i] = vB[i]; }
        }
        __syncthreads();   // b2: release phase-2 writers
        __syncthreads();   // b3: phase-2 slots (waves 3..1 at k=0..2)
#pragma unroll 1
        for (int k = 0; k < 3; ++k) {
            float vA[5], vB[5];
#pragma unroll
            for (int i = 0; i < 5; ++i) {
                float aA = matbuf[k][i * 5][lane]      * uA[0];
                float aB = matbuf[k][i * 5][lane + 64] * uB[0];
#pragma unroll
                for (int l = 1; l < 5; ++l) {
                    aA = fmaf(matbuf[k][i * 5 + l][lane],      uA[l], aA);
                    aB = fmaf(matbuf[k][i * 5 + l][lane + 64], uB[l], aB);
                }
                vA[i] = aA; vB[i] = aB;
            }
#pragma unroll
            for (int i = 0; i < 5; ++i) { uA[i] = vA[i]; uB[i] = vB[i]; }
        }
        float* oA = out + WROFF + (size_t)rowA * 5;        // wR stash (flat)
        float* oB = out + WROFF + (size_t)rowB * 5;
#pragma unroll
        for (int i = 0; i < 5; ++i) { oA[i] = uA[i]; oB[i] = uB[i]; }
    }
}

// ---- stage 2a: res[r] = vL . wR (res overwrites dead pk region of ws) ----
__global__ __launch_bounds__(256)
void finish_dot(const float* __restrict__ outF, float* __restrict__ res)
{
    int r = blockIdx.x * 256 + threadIdx.x;
    const float* vl = outF + (size_t)r * 5;
    const float* wr = outF + WROFF + (size_t)r * 5;
    float s = vl[0] * wr[0];
#pragma unroll
    for (int i = 1; i < 5; ++i) s = fmaf(vl[i], wr[i], s);
    res[r] = s;
}

// ---- stage 2b: out = res*fc_w + fc_b ----
__global__ __launch_bounds__(256)
void finish_out(const float* __restrict__ res, const float* __restrict__ fc_w,
                const float* __restrict__ fc_b, float* __restrict__ out)
{
    int r = blockIdx.x * 256 + threadIdx.x;
    float rv = res[r];
    float* o = out + (size_t)r * NOUT;
#pragma unroll
    for (int j = 0; j < NOUT; ++j) o[j] = fmaf(rv, fc_w[j], fc_b[j]);
}

extern "C" void kernel_launch(void* const* d_in, const int* in_sizes, int n_in,
                              void* d_out, int out_size, void* d_ws, size_t ws_size,
                              hipStream_t stream) {
    const float* x          = (const float*)d_in[0];
    const float* core_first = (const float*)d_in[1];
    const float* cores_mid  = (const float*)d_in[2];
    const float* core_last  = (const float*)d_in[3];
    const float* fc_w       = (const float*)d_in[4];
    const float* fc_b       = (const float*)d_in[5];
    float* out              = (float*)d_out;
    float* pk               = (float*)d_ws;   // 390*100*4 = 156,000 B
    float* res              = (float*)d_ws;   // reuses pk region (dead after main)

    hipLaunchKernelGGL(prepack_pairs, dim3((NPAIR * 100 + 255) / 256), dim3(256),
                       0, stream, cores_mid, pk);
    hipLaunchKernelGGL(mps_half_kernel, dim3(256), dim3(512), 0, stream,
                       x, core_first, cores_mid, core_last, pk, out);
    hipLaunchKernelGGL(finish_dot, dim3(Bn / 256), dim3(256), 0, stream,
                       out, res);
    hipLaunchKernelGGL(finish_out, dim3(Bn / 256), dim3(256), 0, stream,
                       res, fc_w, fc_b, out);
}